// Round 4
// baseline (551.220 us; speedup 1.0000x reference)
//
#include <hip/hip_runtime.h>

// QAttentionLayer: out[..., i] = prod_{j<=i} cos(x_j)*cos(w_j), rows of 10 fp32.
// Memory-bound streaming kernel (335 MB total traffic -> ~53 us floor @6.3TB/s).
//
// Structure (R4 = R3 + compile fix): coalesced float4 global->LDS stage with
// additive swizzle s(L)=L+(L>>3); each thread reads ONE contiguous 80 B chunk
// (= 2 consecutive rows) via 5 conflict-free ds_read_b128, computes in
// registers, stores 5 aligned 16 B nontemporal stores directly to global.
// R3 compile error: __builtin_nontemporal_store rejects HIP_vector_type
// float4 -> use clang ext_vector_type(4) float (bit-identical, 16B-aligned).
//
// Swizzle proof: read k of lane l hits float4 slot s(5l+k); lanes 8 apart
// differ by s(+40) = +45 == 5 (mod 8) -> the 8 aliasing lanes of a wave64
// walk all 8 bank-groups -> conflict-free. Write side: consecutive L ->
// consecutive groups -> conflict-free.

typedef float vf4 __attribute__((ext_vector_type(4)));

#define BLOCK 256
#define NQ 10
#define ROWS_PER_THREAD 2
#define ROWS_PER_BLOCK (BLOCK * ROWS_PER_THREAD)      // 512 rows
#define F4_PER_BLOCK (ROWS_PER_BLOCK * NQ / 4)        // 1280 float4 = 20480 B
#define F4_PER_THREAD (F4_PER_BLOCK / BLOCK)          // 5
#define SWZ(L) ((L) + ((L) >> 3))
#define LDS_F4 (SWZ(F4_PER_BLOCK - 1) + 1)            // 1439 float4 = 23024 B

__global__ __launch_bounds__(BLOCK) void qcircuit_kernel(
    const float* __restrict__ x,
    const float* __restrict__ w,
    float* __restrict__ out,
    long long n_rows)
{
    __shared__ vf4 lds[LDS_F4];

    const int tid = threadIdx.x;
    const long long total_f4 = (n_rows * NQ) / 4;     // n_rows even -> exact
    const long long f4_base  = (long long)blockIdx.x * F4_PER_BLOCK;
    const vf4* __restrict__ gin = (const vf4*)x;

    // ---- coalesced global -> LDS stage (16 B/lane), swizzled slots ----
    #pragma unroll
    for (int k = 0; k < F4_PER_THREAD; ++k) {
        const int L = k * BLOCK + tid;
        const long long gi = f4_base + L;
        if (gi < total_f4) lds[SWZ(L)] = gin[gi];
    }

    // cos(weights): uniform loads -> scalar; 10 v_cos amortized over 2 rows
    float cw[NQ];
    #pragma unroll
    for (int j = 0; j < NQ; ++j) cw[j] = __cosf(w[j]);

    __syncthreads();

    // ---- each thread: 5 conflict-free ds_read_b128 = 2 consecutive rows ----
    float f[4 * F4_PER_THREAD];
    #pragma unroll
    for (int k = 0; k < F4_PER_THREAD; ++k) {
        const vf4 v = lds[SWZ(tid * F4_PER_THREAD + k)];
        f[4 * k + 0] = v.x; f[4 * k + 1] = v.y;
        f[4 * k + 2] = v.z; f[4 * k + 3] = v.w;
    }

    // ---- cumulative product, both rows, in registers ----
    float p0 = 1.0f, p1 = 1.0f;
    #pragma unroll
    for (int j = 0; j < NQ; ++j) {
        p0 *= __cosf(f[j]) * cw[j];
        f[j] = p0;
        p1 *= __cosf(f[NQ + j]) * cw[j];
        f[NQ + j] = p1;
    }

    // ---- direct aligned 16 B nontemporal stores (thread chunk is 80 B) ----
    const long long word_base = f4_base * 4 + (long long)tid * (NQ * ROWS_PER_THREAD);
    vf4* __restrict__ gout = (vf4*)(out + word_base);
    #pragma unroll
    for (int k = 0; k < F4_PER_THREAD; ++k) {
        if (word_base + 4 * k + 3 < n_rows * NQ) {
            vf4 v;
            v.x = f[4 * k + 0]; v.y = f[4 * k + 1];
            v.z = f[4 * k + 2]; v.w = f[4 * k + 3];
            __builtin_nontemporal_store(v, gout + k);
        }
    }
}

extern "C" void kernel_launch(void* const* d_in, const int* in_sizes, int n_in,
                              void* d_out, int out_size, void* d_ws, size_t ws_size,
                              hipStream_t stream) {
    const float* x = (const float*)d_in[0];
    const float* w = (const float*)d_in[1];
    float* out = (float*)d_out;

    const long long n_rows = (long long)in_sizes[0] / NQ;
    const int blocks = (int)((n_rows + ROWS_PER_BLOCK - 1) / ROWS_PER_BLOCK);

    hipLaunchKernelGGL(qcircuit_kernel, dim3(blocks), dim3(BLOCK), 0, stream,
                       x, w, out, n_rows);
}